// Round 9
// baseline (402.059 us; speedup 1.0000x reference)
//
#include <hip/hip_runtime.h>
#include <hip/hip_cooperative_groups.h>
#include <hip/hip_bf16.h>

namespace cg = cooperative_groups;

#define N_PTS  4096
#define M_Q    16384
#define C_IN   256
#define C_SKIP 128
#define C_H    384      // C_IN + C_SKIP
#define HDIM   256
#define NSPLIT 32
#define PTS_PER_SPLIT (N_PTS / NSPLIT)   // 128
#define GRID   512      // 2 blocks/CU needed — large co-residency margin

typedef __bf16 bf16x8 __attribute__((ext_vector_type(8)));
typedef __bf16 bf16x4 __attribute__((ext_vector_type(4)));
typedef float  f32x4  __attribute__((ext_vector_type(4)));

__device__ __forceinline__ __bf16 tobf(float f) {
    __hip_bfloat16 h = __float2bfloat16(f);
    __bf16 r;
    __builtin_memcpy(&r, &h, 2);
    return r;
}

__device__ __forceinline__ void insert3(float d, int j,
                                        float& b0, float& b1, float& b2,
                                        int& i0, int& i1, int& i2) {
    if (d < b2) {
        if (d < b1) {
            b2 = b1; i2 = i1;
            if (d < b0) { b1 = b0; i1 = i0; b0 = d; i0 = j; }
            else        { b1 = d;  i1 = j; }
        } else { b2 = d; i2 = j; }
    }
}

// ============================================================================
// Shared phase bodies (used by both the mega kernel and the fallback kernels)
// ============================================================================

__device__ __forceinline__ void prep_body(int i,
        const float* __restrict__ W1, const float* __restrict__ W2,
        const float* __restrict__ pos,
        __bf16* __restrict__ W1t, __bf16* __restrict__ W2t,
        float4* __restrict__ pos4) {
    if (i < C_H * HDIM) {
        const int k = i / HDIM, n = i % HDIM;
        W1t[n * C_H + k] = tobf(W1[i]);
    } else if (i < C_H * HDIM + HDIM * HDIM) {
        const int j = i - C_H * HDIM;
        const int k = j / HDIM, n = j % HDIM;
        W2t[n * HDIM + k] = tobf(W2[j]);
    } else if (i < C_H * HDIM + HDIM * HDIM + N_PTS) {
        const int j = i - (C_H * HDIM + HDIM * HDIM);
        const float px = pos[j*3+0], py = pos[j*3+1], pz = pos[j*3+2];
        pos4[j] = make_float4(px, py, pz, px*px + py*py + pz*pz);
    }
}

// kNN partial scan: one (split s, query-block xb) unit, 2 queries/thread.
__device__ __forceinline__ void knn_body(int s, int xb, int t,
        const float4* __restrict__ pos4, const float* __restrict__ pos_skip,
        float* __restrict__ cand_d, int* __restrict__ cand_i) {
    const int qa = xb * 512 + t;
    const int qb2 = qa + 256;
    const int j0 = s * PTS_PER_SPLIT;
    const float ax = -2.0f * pos_skip[qa*3+0];
    const float ay = -2.0f * pos_skip[qa*3+1];
    const float az = -2.0f * pos_skip[qa*3+2];
    const float bx = -2.0f * pos_skip[qb2*3+0];
    const float by = -2.0f * pos_skip[qb2*3+1];
    const float bz = -2.0f * pos_skip[qb2*3+2];
    float A0 = 3e38f, A1 = 3e38f, A2 = 3e38f;
    float B0 = 3e38f, B1 = 3e38f, B2 = 3e38f;
    int   ia0 = 0, ia1 = 0, ia2 = 0, ib0 = 0, ib1 = 0, ib2 = 0;
    #pragma unroll 8
    for (int j = 0; j < PTS_PER_SPLIT; ++j) {
        const float4 p = pos4[j0 + j];      // uniform address -> broadcast load
        const float dA = fmaf(p.x, ax, fmaf(p.y, ay, fmaf(p.z, az, p.w)));
        const float dB = fmaf(p.x, bx, fmaf(p.y, by, fmaf(p.z, bz, p.w)));
        const int  jj = j0 + j;
        {
            const bool c2 = dA < A2, c1 = dA < A1, c0 = dA < A0;
            A2 = c2 ? (c1 ? A1 : dA) : A2;  ia2 = c2 ? (c1 ? ia1 : jj) : ia2;
            A1 = c1 ? (c0 ? A0 : dA) : A1;  ia1 = c1 ? (c0 ? ia0 : jj) : ia1;
            A0 = c0 ? dA : A0;              ia0 = c0 ? jj : ia0;
        }
        {
            const bool c2 = dB < B2, c1 = dB < B1, c0 = dB < B0;
            B2 = c2 ? (c1 ? B1 : dB) : B2;  ib2 = c2 ? (c1 ? ib1 : jj) : ib2;
            B1 = c1 ? (c0 ? B0 : dB) : B1;  ib1 = c1 ? (c0 ? ib0 : jj) : ib1;
            B0 = c0 ? dB : B0;              ib0 = c0 ? jj : ib0;
        }
    }
    const int SM = NSPLIT * M_Q;
    const int basea = s * M_Q + qa;         // SoA rank-major, coalesced
    const int baseb = s * M_Q + qb2;
    cand_d[0*SM + basea] = A0;  cand_d[0*SM + baseb] = B0;
    cand_d[1*SM + basea] = A1;  cand_d[1*SM + baseb] = B1;
    cand_d[2*SM + basea] = A2;  cand_d[2*SM + baseb] = B2;
    cand_i[0*SM + basea] = ia0; cand_i[0*SM + baseb] = ib0;
    cand_i[1*SM + basea] = ia1; cand_i[1*SM + baseb] = ib1;
    cand_i[2*SM + basea] = ia2; cand_i[2*SM + baseb] = ib2;
}

// merge + interp + tail for 64 queries starting at m0. sIdx:[64][3] sW:[64][3]
__device__ __forceinline__ void merge_interp_body(int m0, int t,
        int* sIdx, float* sW,
        const float* __restrict__ cand_d, const int* __restrict__ cand_i,
        const float* __restrict__ pos, const float* __restrict__ pos_skip,
        const float* __restrict__ x, const float* __restrict__ x_skip,
        __bf16* __restrict__ h, float* __restrict__ out, int out_size,
        int nblocks, int bid) {
    const int ql = t >> 2, l = t & 3;
    const int q  = m0 + ql;
    float b0 = 3e38f, b1 = 3e38f, b2 = 3e38f;
    int   i0 = 0, i1 = 0, i2 = 0;
    const int SM = NSPLIT * M_Q;
    #pragma unroll
    for (int u = 0; u < NSPLIT/4; ++u) {
        const int s = l * (NSPLIT/4) + u;   // ascending split order, tie-break safe
        const int base = s * M_Q + q;
        const float d0 = cand_d[0*SM + base], d1 = cand_d[1*SM + base], d2c = cand_d[2*SM + base];
        const int   j0 = cand_i[0*SM + base], j1 = cand_i[1*SM + base], j2c = cand_i[2*SM + base];
        insert3(d0, j0,  b0,b1,b2, i0,i1,i2);
        insert3(d1, j1,  b0,b1,b2, i0,i1,i2);
        insert3(d2c, j2c, b0,b1,b2, i0,i1,i2);
    }
    #pragma unroll
    for (int m = 1; m <= 2; m <<= 1) {
        const float nb0 = __shfl_xor(b0, m), nb1 = __shfl_xor(b1, m), nb2 = __shfl_xor(b2, m);
        const int   ni0 = __shfl_xor(i0, m), ni1 = __shfl_xor(i1, m), ni2 = __shfl_xor(i2, m);
        const bool upper = (l & m) != 0;
        float e0 = upper ? b0 : nb0, e1 = upper ? b1 : nb1, e2 = upper ? b2 : nb2;
        int   f0 = upper ? i0 : ni0, f1 = upper ? i1 : ni1, f2 = upper ? i2 : ni2;
        if (upper) { b0 = nb0; b1 = nb1; b2 = nb2; i0 = ni0; i1 = ni1; i2 = ni2; }
        insert3(e0, f0, b0,b1,b2, i0,i1,i2);
        insert3(e1, f1, b0,b1,b2, i0,i1,i2);
        insert3(e2, f2, b0,b1,b2, i0,i1,i2);
    }
    if (l == 0) {
        const float qx = pos_skip[q*3+0], qy = pos_skip[q*3+1], qz = pos_skip[q*3+2];
        float wv[3]; int ii[3] = {i0, i1, i2};
        float wsum = 0.0f;
        #pragma unroll
        for (int r = 0; r < 3; ++r) {
            const float dx = qx - pos[ii[r]*3+0];
            const float dy = qy - pos[ii[r]*3+1];
            const float dz = qz - pos[ii[r]*3+2];
            const float d2 = dx*dx + dy*dy + dz*dz;   // exact recompute = reference d2k
            wv[r] = 1.0f / fmaxf(d2, 1e-16f);
            wsum += wv[r];
        }
        const float inv = 1.0f / wsum;
        #pragma unroll
        for (int r = 0; r < 3; ++r) { sIdx[ql*3+r] = ii[r]; sW[ql*3+r] = wv[r] * inv; }
    }
    __syncthreads();

    // interp: 64 rows x 96 float4-cols (cols 0..63 interp, 64..95 skip)
    #pragma unroll 4
    for (int g = 0; g < 24; ++g) {
        const int flat = g * 256 + t;
        const int r  = flat / 96;
        const int c4 = flat % 96;
        const int m  = m0 + r;
        if (c4 < 64) {
            const int c = c4 * 4;
            const int   j0 = sIdx[r*3+0], j1 = sIdx[r*3+1], j2 = sIdx[r*3+2];
            const float w0 = sW[r*3+0],   w1 = sW[r*3+1],   w2 = sW[r*3+2];
            const float4 v0 = *(const float4*)(x + (size_t)j0 * C_IN + c);
            const float4 v1 = *(const float4*)(x + (size_t)j1 * C_IN + c);
            const float4 v2 = *(const float4*)(x + (size_t)j2 * C_IN + c);
            bf16x4 o;
            o[0] = tobf(w0*v0.x + w1*v1.x + w2*v2.x);
            o[1] = tobf(w0*v0.y + w1*v1.y + w2*v2.y);
            o[2] = tobf(w0*v0.z + w1*v1.z + w2*v2.z);
            o[3] = tobf(w0*v0.w + w1*v1.w + w2*v2.w);
            *(bf16x4*)(h + (size_t)m * C_H + c) = o;
        } else {
            const int c = (c4 - 64) * 4;
            const float4 v = *(const float4*)(x_skip + (size_t)m * C_SKIP + c);
            bf16x4 o;
            o[0] = tobf(v.x); o[1] = tobf(v.y); o[2] = tobf(v.z); o[3] = tobf(v.w);
            *(bf16x4*)(h + (size_t)m * C_H + C_IN + c) = o;
        }
    }

    // tail: pos_skip passthrough slice + batch zeros slice
    if (t < 64 * 3)
        out[(size_t)M_Q * HDIM + m0*3 + t] = pos_skip[m0*3 + t];
    const int zbase = M_Q * HDIM + M_Q * 3;
    const int ztot  = out_size - zbase;
    const int chunk = (ztot + nblocks - 1) / nblocks;
    for (int iz = t; iz < chunk; iz += 256) {
        const int gi = bid * chunk + iz;
        if (gi < ztot) out[zbase + gi] = 0.0f;
    }
}

// GEMM tile: BM=64 x BN=128, BK=32, dbuf single-barrier + reg prefetch.
// As: [2][64][40] at smem el 0; Bs: [2][128][40] at smem el 5120. 30720 B.
template<bool RELU, int KDIM, typename OUT_T>
__device__ __forceinline__ void gemm_body(int m0, int n0, int t,
        __bf16* smem,
        const __bf16* __restrict__ A, const __bf16* __restrict__ Bt,
        const float* __restrict__ bias, OUT_T* __restrict__ C) {
    __bf16* As = smem;            // [2][64][40]
    __bf16* Bs = smem + 5120;     // [2][128][40]
    const int w    = t >> 6;
    const int lane = t & 63;
    const int ln = lane & 15, kq = lane >> 4;
    const int wm = (w >> 1) * 32;
    const int wn = (w & 1) * 64;
    const int rA = t >> 1, cA = (t & 1) * 16;

    constexpr int KS = KDIM / 32;
    int4 a0{}, a1{}, b0v, b1v;
    if (t < 128) {
        a0 = *(const int4*)(A + (size_t)(m0 + rA) * KDIM + cA);
        a1 = *(const int4*)(A + (size_t)(m0 + rA) * KDIM + cA + 8);
    }
    b0v = *(const int4*)(Bt + (size_t)(n0 + rA) * KDIM + cA);
    b1v = *(const int4*)(Bt + (size_t)(n0 + rA) * KDIM + cA + 8);

    f32x4 acc[2][4] = {};

    for (int ks = 0; ks < KS; ++ks) {
        const int p = ks & 1;
        if (t < 128) {
            *(int4*)&As[p*2560 + rA*40 + cA]     = a0;
            *(int4*)&As[p*2560 + rA*40 + cA + 8] = a1;
        }
        *(int4*)&Bs[p*5120 + rA*40 + cA]     = b0v;
        *(int4*)&Bs[p*5120 + rA*40 + cA + 8] = b1v;
        __syncthreads();
        if (ks + 1 < KS) {                      // prefetch next tile a step early
            const int k0 = (ks + 1) * 32;
            if (t < 128) {
                a0 = *(const int4*)(A + (size_t)(m0 + rA) * KDIM + k0 + cA);
                a1 = *(const int4*)(A + (size_t)(m0 + rA) * KDIM + k0 + cA + 8);
            }
            b0v = *(const int4*)(Bt + (size_t)(n0 + rA) * KDIM + k0 + cA);
            b1v = *(const int4*)(Bt + (size_t)(n0 + rA) * KDIM + k0 + cA + 8);
        }
        bf16x8 af[2], bfv[4];
        #pragma unroll
        for (int mt = 0; mt < 2; ++mt)
            af[mt] = *(const bf16x8*)&As[p*2560 + (wm + mt*16 + ln)*40 + kq*8];
        #pragma unroll
        for (int nt = 0; nt < 4; ++nt)
            bfv[nt] = *(const bf16x8*)&Bs[p*5120 + (wn + nt*16 + ln)*40 + kq*8];
        #pragma unroll
        for (int mt = 0; mt < 2; ++mt)
            #pragma unroll
            for (int nt = 0; nt < 4; ++nt)
                acc[mt][nt] = __builtin_amdgcn_mfma_f32_16x16x32_bf16(
                                  af[mt], bfv[nt], acc[mt][nt], 0, 0, 0);
    }

    #pragma unroll
    for (int nt = 0; nt < 4; ++nt) {
        const int n = n0 + wn + nt*16 + ln;
        const float bv = bias[n];
        #pragma unroll
        for (int mt = 0; mt < 2; ++mt) {
            const int mbase = m0 + wm + mt*16 + kq*4;
            #pragma unroll
            for (int r = 0; r < 4; ++r) {
                float v = acc[mt][nt][r] + bv;
                if (RELU) v = fmaxf(v, 0.0f);
                C[(size_t)(mbase + r) * 256 + n] = (OUT_T)v;
            }
        }
    }
}

// ============================================================================
// Mega kernel (cooperative, GRID=512)
// ============================================================================
__global__ __launch_bounds__(256, 4) void mega_kernel(
        const float* __restrict__ x, const float* __restrict__ pos,
        const float* __restrict__ x_skip, const float* __restrict__ pos_skip,
        const float* __restrict__ W1, const float* __restrict__ b1,
        const float* __restrict__ W2, const float* __restrict__ b2,
        float* __restrict__ out, int out_size,
        float* __restrict__ cand_d, int* __restrict__ cand_i,
        __bf16* __restrict__ h, __bf16* __restrict__ hid,
        __bf16* __restrict__ W1t, __bf16* __restrict__ W2t,
        float4* __restrict__ pos4) {
    __shared__ __align__(16) char smem[30720];
    cg::grid_group grid = cg::this_grid();
    const int b = blockIdx.x;
    const int t = threadIdx.x;

    // Phase 0: prep (167936 elems, stride loop)
    for (int i = b * 256 + t; i < C_H*HDIM + HDIM*HDIM + N_PTS; i += GRID * 256)
        prep_body(i, W1, W2, pos, W1t, W2t, pos4);
    grid.sync();

    // Phase 1: kNN — 1024 units, 2 per block
    for (int u = b; u < NSPLIT * 32; u += GRID)
        knn_body(u >> 5, u & 31, t, pos4, pos_skip, cand_d, cand_i);
    grid.sync();

    // Phase 2: merge + interp + tail — 256 units of 64 queries
    if (b < 256)
        merge_interp_body(b * 64, t, (int*)smem, (float*)(smem + 768),
                          cand_d, cand_i, pos, pos_skip, x, x_skip,
                          h, out, out_size, 256, b);
    grid.sync();

    // Phase 3: GEMM1 + ReLU — 512 tiles, 1 per block
    gemm_body<true, C_H, __bf16>((b >> 1) * 64, (b & 1) * 128, t,
                                 (__bf16*)smem, h, W1t, b1, hid);
    grid.sync();

    // Phase 4: GEMM2 — 512 tiles, 1 per block
    gemm_body<false, HDIM, float>((b >> 1) * 64, (b & 1) * 128, t,
                                  (__bf16*)smem, hid, W2t, b2, out);
}

// ============================================================================
// Fallback kernels (verbatim R7 structure)
// ============================================================================
__global__ __launch_bounds__(256) void prep_kernel(
        const float* __restrict__ W1, const float* __restrict__ W2,
        const float* __restrict__ pos,
        __bf16* __restrict__ W1t, __bf16* __restrict__ W2t,
        float4* __restrict__ pos4) {
    prep_body(blockIdx.x * 256 + threadIdx.x, W1, W2, pos, W1t, W2t, pos4);
}

__global__ __launch_bounds__(256) void knn_part_kernel(
        const float4* __restrict__ pos4, const float* __restrict__ pos_skip,
        float* __restrict__ cand_d, int* __restrict__ cand_i) {
    knn_body(blockIdx.y, blockIdx.x, threadIdx.x, pos4, pos_skip, cand_d, cand_i);
}

__global__ __launch_bounds__(256) void merge_interp_kernel(
        const float* __restrict__ cand_d, const int* __restrict__ cand_i,
        const float* __restrict__ pos, const float* __restrict__ pos_skip,
        const float* __restrict__ x, const float* __restrict__ x_skip,
        __bf16* __restrict__ h, float* __restrict__ out, int out_size) {
    __shared__ int   sIdx[64 * 3];
    __shared__ float sW[64 * 3];
    merge_interp_body(blockIdx.x * 64, threadIdx.x, sIdx, sW,
                      cand_d, cand_i, pos, pos_skip, x, x_skip,
                      h, out, out_size, 256, blockIdx.x);
}

template<bool RELU, int KDIM, typename OUT_T>
__global__ __launch_bounds__(256) void gemm_bf16_kernel(
        const __bf16* __restrict__ A, const __bf16* __restrict__ Bt,
        const float* __restrict__ bias, OUT_T* __restrict__ C) {
    __shared__ __align__(16) __bf16 smem[15360];
    gemm_body<RELU, KDIM, OUT_T>(blockIdx.y * 64, blockIdx.x * 128, threadIdx.x,
                                 smem, A, Bt, bias, C);
}

extern "C" void kernel_launch(void* const* d_in, const int* in_sizes, int n_in,
                              void* d_out, int out_size, void* d_ws, size_t ws_size,
                              hipStream_t stream) {
    (void)in_sizes; (void)n_in; (void)ws_size;
    const float* x        = (const float*)d_in[0];   // [4096,256]
    const float* pos      = (const float*)d_in[1];   // [4096,3]
    const float* x_skip   = (const float*)d_in[3];   // [16384,128]
    const float* pos_skip = (const float*)d_in[4];   // [16384,3]
    const float* W1       = (const float*)d_in[6];   // [384,256]
    const float* b1       = (const float*)d_in[7];   // [256]
    const float* W2       = (const float*)d_in[8];   // [256,256]
    const float* b2       = (const float*)d_in[9];   // [256]
    float* out = (float*)d_out;

    char* ws = (char*)d_ws;
    float*  cand_d = (float*) (ws);                  // M*96*4 = 6,291,456
    int*    cand_i = (int*)   (ws + 6291456);        // 6,291,456
    __bf16* h      = (__bf16*)(ws + 12582912);       // M*384*2 = 12,582,912
    __bf16* hid    = (__bf16*)(ws + 25165824);       // M*256*2 =  8,388,608
    __bf16* W1t    = (__bf16*)(ws + 33554432);       //   196,608 (n-major)
    __bf16* W2t    = (__bf16*)(ws + 33751040);       //   131,072 (n-major)
    float4* pos4   = (float4*)(ws + 33882112);       //    65,536

    // Deterministic cooperative-launch feasibility check (host-side, capture-safe)
    bool coop = false;
    int numCU = 0, maxBlk = 0;
    if (hipDeviceGetAttribute(&numCU, hipDeviceAttributeMultiprocessorCount, 0) == hipSuccess &&
        hipOccupancyMaxActiveBlocksPerMultiprocessor(&maxBlk, (const void*)mega_kernel, 256, 0) == hipSuccess) {
        coop = ((long)numCU * maxBlk >= GRID);
    }

    if (coop) {
        void* args[] = {
            (void*)&x, (void*)&pos, (void*)&x_skip, (void*)&pos_skip,
            (void*)&W1, (void*)&b1, (void*)&W2, (void*)&b2,
            (void*)&out, (void*)&out_size,
            (void*)&cand_d, (void*)&cand_i, (void*)&h, (void*)&hid,
            (void*)&W1t, (void*)&W2t, (void*)&pos4
        };
        if (hipLaunchCooperativeKernel((const void*)mega_kernel,
                                       dim3(GRID), dim3(256), args, 0, stream) != hipSuccess)
            coop = false;                    // nothing launched; take fallback
    }

    if (!coop) {
        prep_kernel     <<<(C_H*HDIM + HDIM*HDIM + N_PTS + 255)/256, 256, 0, stream>>>(
            W1, W2, pos, W1t, W2t, pos4);
        knn_part_kernel <<<dim3(M_Q/512, NSPLIT), 256, 0, stream>>>(pos4, pos_skip, cand_d, cand_i);
        merge_interp_kernel<<<M_Q/64, 256, 0, stream>>>(
            cand_d, cand_i, pos, pos_skip, x, x_skip, h, out, out_size);
        gemm_bf16_kernel<true, C_H, __bf16><<<dim3(2, M_Q/64), 256, 0, stream>>>(
            h, W1t, b1, hid);
        gemm_bf16_kernel<false, HDIM, float><<<dim3(2, M_Q/64), 256, 0, stream>>>(
            hid, W2t, b2, out);
    }
}